// Round 9
// baseline (533.060 us; speedup 1.0000x reference)
//
#include <hip/hip_runtime.h>

#define TT 20
#define HH 64
#define EB 512         // deg-histogram blocks fused ahead of RNN blocks

typedef __attribute__((ext_vector_type(8))) short short8;   // 8 bf16 (MFMA A/B frag)
typedef __attribute__((ext_vector_type(4))) float f32x4;    // MFMA C/D frag

__device__ __forceinline__ float fast_tanh(float a) {
    a = fminf(fmaxf(a, -12.0f), 12.0f);
    float e = __builtin_amdgcn_exp2f(a * 2.885390081777927f);
    return (e - 1.0f) * __builtin_amdgcn_rcpf(e + 1.0f);
}

__device__ __forceinline__ unsigned fbits(float f) { union { float f; unsigned u; } v; v.f = f; return v.u; }
__device__ __forceinline__ float bcast(unsigned u) { union { float f; unsigned u; } v; v.u = u; return v.f; }

// k_prep (single block, 256 thr): W_hh split hi/lo bf16 in MFMA B-frag order + v = W_gcn^T w_fc
// Frag order: q = ((tt2*2+kc)*64 + lane)*8 + j  <->  W[16*tt2 + (lane&15)][kc*32 + (lane>>4)*8 + j]
__global__ __launch_bounds__(256) void k_prep(const float* __restrict__ W_hh,
                                              const float* __restrict__ W_gcn,
                                              const float* __restrict__ W_fc,
                                              unsigned short* __restrict__ Whi,
                                              unsigned short* __restrict__ Wlo,
                                              float* __restrict__ v) {
    const int t = threadIdx.x;
    for (int q = t; q < HH * HH; q += 256) {
        int j    = q & 7;
        int lane = (q >> 3) & 63;
        int fc   = q >> 9;              // tt2*2+kc
        int tt2  = fc >> 1, kc = fc & 1;
        int row  = 16 * tt2 + (lane & 15);
        int col  = kc * 32 + (lane >> 4) * 8 + j;
        float w  = W_hh[row * HH + col];
        unsigned u  = fbits(w);
        unsigned hb = u & 0xffff0000u;           // trunc-split: hi
        float lo = w - bcast(hb);
        Whi[q] = (unsigned short)(hb >> 16);
        Wlo[q] = (unsigned short)(fbits(lo) >> 16);
    }
    if (t < HH) {
        float a = 0.0f;
#pragma unroll 8
        for (int j = 0; j < HH; ++j) a = fmaf(W_fc[j], W_gcn[j * HH + t], a);
        v[t] = a;
    }
}

// Fused: blocks [0,EB) build deg histogram; blocks >= EB run the MFMA RNN.
// RNN block = 4 independent waves, 16 nodes each, wave-private LDS, no barriers.
__global__ __launch_bounds__(256, 4) void k_fused(
    const float* __restrict__ x,
    const float* __restrict__ W_ih, const float* __restrict__ b_ih,
    const float* __restrict__ b_hh,
    const unsigned short* __restrict__ Whi, const unsigned short* __restrict__ Wlo,
    const float* __restrict__ v, const int* __restrict__ ei,
    int* __restrict__ degi, float* __restrict__ z,
    int N, int E)
{
    // per-wave slices; h stored in A-frag-linear order with XOR-swizzle:
    // element (m,k): kc=k/32, qa=(k%32)/8, la=m+16*qa, addr = kc*512 + (la^((la>>4)&1))*8 + k%8
    __shared__ __align__(16) unsigned short sHh[4][1024];
    __shared__ __align__(16) unsigned short sHl[4][1024];
    __shared__ __align__(16) float sX[4][16 * TT];

    const int t = threadIdx.x;

    if (blockIdx.x < EB) {
        for (int e = blockIdx.x * 256 + t; e < E; e += EB * 256) {
            int2 p = ((const int2*)ei)[e];
            atomicAdd(&degi[p.y], 1);
        }
        return;
    }

    const int w    = t >> 6;          // wave id 0..3
    const int l    = t & 63;          // lane
    const int nl   = l & 15;
    const int quad = l >> 4;
    const int n0   = (blockIdx.x - EB) * 64 + w * 16;

    unsigned short* hh = sHh[w];
    unsigned short* hl = sHl[w];
    float*          sx = sX[w];

    // stage x: 16 nodes x 20 steps, transposed to [step][node]
    for (int i = l; i < 16 * TT; i += 64) {
        int nn = i / TT, tt = i - nn * TT;
        int n = n0 + nn; if (n >= N) n = N - 1;
        sx[tt * 16 + nn] = x[(size_t)n * TT + tt];
    }
    // zero h (hi+lo = 1024 dwords per wave)
    {
        uint4 zz = {0, 0, 0, 0};
        uint4* ph = (uint4*)hh;
        uint4* pl = (uint4*)hl;
#pragma unroll
        for (int i = 0; i < 2; ++i) { ph[l + 64 * i] = zz; pl[l + 64 * i] = zz; }
    }

    // W fragments: direct b128 loads from pre-split frag-order arrays
    short8 Bh[4][2], Bl[4][2];
#pragma unroll
    for (int tt2 = 0; tt2 < 4; ++tt2)
#pragma unroll
        for (int kc = 0; kc < 2; ++kc) {
            int base = ((tt2 * 2 + kc) * 64 + l) * 8;
            Bh[tt2][kc] = *(const short8*)&Whi[base];
            Bl[tt2][kc] = *(const short8*)&Wlo[base];
        }

    float wih4[4], bs4[4], vv[4];
    {
        float vl = v[l];
#pragma unroll
        for (int tt2 = 0; tt2 < 4; ++tt2) {
            int n = nl + 16 * tt2;
            wih4[tt2] = W_ih[n];
            bs4[tt2]  = b_ih[n] + b_hh[n];
            vv[tt2]   = __shfl(vl, n, 64);
        }
    }

    // A-read address (shorts): kc*512 + (l ^ ((l>>4)&1))*8
    const int ra = (l ^ ((l >> 4) & 1)) * 8;

    f32x4 C[4];

    for (int step = 0; step < TT; ++step) {
        const float4 xr = *(const float4*)&sx[step * 16 + quad * 4];
#pragma unroll
        for (int tt2 = 0; tt2 < 4; ++tt2) {
            C[tt2][0] = fmaf(xr.x, wih4[tt2], bs4[tt2]);
            C[tt2][1] = fmaf(xr.y, wih4[tt2], bs4[tt2]);
            C[tt2][2] = fmaf(xr.z, wih4[tt2], bs4[tt2]);
            C[tt2][3] = fmaf(xr.w, wih4[tt2], bs4[tt2]);
        }

#pragma unroll
        for (int kc = 0; kc < 2; ++kc) {
            short8 Ah = *(const short8*)&hh[kc * 512 + ra];
            short8 Al = *(const short8*)&hl[kc * 512 + ra];
#pragma unroll
            for (int tt2 = 0; tt2 < 4; ++tt2) {
                C[tt2] = __builtin_amdgcn_mfma_f32_16x16x32_bf16(Ah, Bh[tt2][kc], C[tt2], 0, 0, 0);
                C[tt2] = __builtin_amdgcn_mfma_f32_16x16x32_bf16(Ah, Bl[tt2][kc], C[tt2], 0, 0, 0);
                C[tt2] = __builtin_amdgcn_mfma_f32_16x16x32_bf16(Al, Bh[tt2][kc], C[tt2], 0, 0, 0);
            }
        }

        // tanh + trunc-split + neighbor-pack + swizzled write back
#pragma unroll
        for (int tt2 = 0; tt2 < 4; ++tt2) {
            const int kc_d = tt2 >> 1;
            const int qa   = (nl >> 3) + 2 * (tt2 & 1);
#pragma unroll
            for (int r = 0; r < 4; ++r) {
                float hv = fast_tanh(C[tt2][r]);
                C[tt2][r] = hv;
                unsigned um = fbits(hv);
                unsigned un = (unsigned)__shfl_xor((int)um, 1, 64);
                if (!(nl & 1)) {
                    unsigned hiw = (um >> 16) | (un & 0xffff0000u);
                    float lm = hv - bcast(um & 0xffff0000u);
                    float ln = bcast(un) - bcast(un & 0xffff0000u);
                    unsigned low = (fbits(lm) >> 16) | (fbits(ln) & 0xffff0000u);
                    const int m  = quad * 4 + r;
                    const int la = m + 16 * qa;
                    const int idx = kc_d * 512 + (la ^ ((la >> 4) & 1)) * 8 + (nl & 7);
                    *(unsigned*)&hh[idx] = hiw;
                    *(unsigned*)&hl[idx] = low;
                }
            }
        }
    }

    // z[node] = h . v ; C holds fp32 h (row=quad*4+r, col=nl+16*tt2)
#pragma unroll
    for (int r = 0; r < 4; ++r) {
        float p = 0.0f;
#pragma unroll
        for (int tt2 = 0; tt2 < 4; ++tt2) p = fmaf(C[tt2][r], vv[tt2], p);
        p += __shfl_xor(p, 1, 64);
        p += __shfl_xor(p, 2, 64);
        p += __shfl_xor(p, 4, 64);
        p += __shfl_xor(p, 8, 64);
        if (nl == 0) {
            const int n = n0 + quad * 4 + r;
            if (n < N) z[n] = p;
        }
    }
}

// w[n] = rsqrt(deg[n]+1) * z[n]
__global__ void k_w(const int* __restrict__ degi, const float* __restrict__ z,
                    float* __restrict__ w, int N) {
    int n = blockIdx.x * blockDim.x + threadIdx.x;
    if (n < N) w[n] = __frsqrt_rn((float)degi[n] + 1.0f) * z[n];
}

// S[d] += w[s] — 1 edge/thread, coalesced int2 (R2-calibrated fast shape)
__global__ void k_edge(const int* __restrict__ ei, const float* __restrict__ w,
                       float* __restrict__ S, int E) {
    int e = blockIdx.x * blockDim.x + threadIdx.x;
    if (e >= E) return;
    int2 p = ((const int2*)ei)[e];
    atomicAdd(&S[p.y], w[p.x]);
}

// out = dinv*(S + dinv*z) + c,  c = w_fc.b_gcn + b_fc
__global__ void k_final(const int* __restrict__ degi, const float* __restrict__ S,
                        const float* __restrict__ z,
                        const float* __restrict__ b_gcn, const float* __restrict__ W_fc,
                        const float* __restrict__ b_fc,
                        float* __restrict__ out, int N)
{
    float c = b_fc[0];
#pragma unroll 8
    for (int j = 0; j < HH; ++j) c = fmaf(W_fc[j], b_gcn[j], c);
    int n = blockIdx.x * blockDim.x + threadIdx.x;
    if (n >= N) return;
    float d = __frsqrt_rn((float)degi[n] + 1.0f);
    out[n] = fmaf(d, S[n] + d * z[n], c);
}

extern "C" void kernel_launch(void* const* d_in, const int* in_sizes, int n_in,
                              void* d_out, int out_size, void* d_ws, size_t ws_size,
                              hipStream_t stream)
{
    const float* x     = (const float*)d_in[0];
    const int*   ei    = (const int*)d_in[1];
    const float* W_ih  = (const float*)d_in[2];
    const float* b_ih  = (const float*)d_in[3];
    const float* W_hh  = (const float*)d_in[4];
    const float* b_hh  = (const float*)d_in[5];
    const float* W_gcn = (const float*)d_in[6];
    const float* b_gcn = (const float*)d_in[7];
    const float* W_fc  = (const float*)d_in[8];
    const float* b_fc  = (const float*)d_in[9];
    float* out = (float*)d_out;

    const int N = in_sizes[0] / TT;
    const int E = in_sizes[1] / 2;

    char* ws = (char*)d_ws;
    size_t off = 0;
    auto alloc = [&](size_t bytes) { void* p = ws + off; off += (bytes + 255) & ~(size_t)255; return p; };
    int*   degi = (int*)  alloc((size_t)N * 4);
    float* S    = (float*)alloc((size_t)N * 4);
    float* z    = (float*)alloc((size_t)N * 4);
    float* w    = (float*)alloc((size_t)N * 4);
    float* v    = (float*)alloc(HH * 4);
    unsigned short* Whi = (unsigned short*)alloc(HH * HH * 2);
    unsigned short* Wlo = (unsigned short*)alloc(HH * HH * 2);

    // degi and S adjacent: one memset zeroes both
    size_t span = (size_t)((char*)(S + N) - (char*)degi);
    hipMemsetAsync(degi, 0, span, stream);

    k_prep <<<1, 256, 0, stream>>>(W_hh, W_gcn, W_fc, Whi, Wlo, v);
    const int rnnBlocks = (N + 63) / 64;
    k_fused<<<EB + rnnBlocks, 256, 0, stream>>>(x, W_ih, b_ih, b_hh,
                                                Whi, Wlo, v, ei, degi, z, N, E);
    k_w    <<<(N + 255) / 256, 256, 0, stream>>>(degi, z, w, N);
    k_edge <<<(E + 255) / 256, 256, 0, stream>>>(ei, w, S, E);
    k_final<<<(N + 255) / 256, 256, 0, stream>>>(degi, S, z, b_gcn, W_fc, b_fc, out, N);
}

// Round 10
// 429.948 us; speedup vs baseline: 1.2398x; 1.2398x over previous
//
#include <hip/hip_runtime.h>

#define TT 20
#define HH 64
#define EPB 2048       // edges handled (as deg atomics) per RNN block = 8 per thread

typedef __attribute__((ext_vector_type(8))) short short8;   // 8 bf16 (MFMA A/B frag)
typedef __attribute__((ext_vector_type(4))) float f32x4;    // MFMA C/D frag

__device__ __forceinline__ float fast_tanh(float a) {
    a = fminf(fmaxf(a, -12.0f), 12.0f);
    float e = __builtin_amdgcn_exp2f(a * 2.885390081777927f);
    return (e - 1.0f) * __builtin_amdgcn_rcpf(e + 1.0f);
}

__device__ __forceinline__ unsigned fbits(float f) { union { float f; unsigned u; } v; v.f = f; return v.u; }
__device__ __forceinline__ float bcast(unsigned u) { union { float f; unsigned u; } v; v.u = u; return v.f; }

// Single fused kernel: every block = 4 independent RNN waves (16 nodes each,
// wave-private LDS, no barriers) + a 2048-edge slice of the deg histogram,
// fire-and-forget atomics interleaved between step chunks.
__global__ __launch_bounds__(256, 3) void k_fused(
    const float* __restrict__ x,
    const float* __restrict__ W_ih, const float* __restrict__ b_ih,
    const float* __restrict__ W_hh, const float* __restrict__ b_hh,
    const float* __restrict__ W_gcn, const float* __restrict__ W_fc,
    const int* __restrict__ ei,
    int* __restrict__ degi, float* __restrict__ z,
    int N, int E)
{
    // per-wave slices; h in A-frag-linear order with XOR swizzle:
    // element (m,k): kc=k/32, qa=(k%32)/8, la=m+16*qa, addr = kc*512 + (la^((la>>4)&1))*8 + k%8
    __shared__ __align__(16) unsigned short sHh[4][1024];
    __shared__ __align__(16) unsigned short sHl[4][1024];
    __shared__ __align__(16) float sX[4][16 * TT];

    const int t    = threadIdx.x;
    const int w    = t >> 6;
    const int l    = t & 63;
    const int nl   = l & 15;
    const int quad = l >> 4;
    const int n0   = blockIdx.x * 64 + w * 16;

    unsigned short* hh = sHh[w];
    unsigned short* hl = sHl[w];
    float*          sx = sX[w];

    // ---- edge slice loads (coalesced int2), sentinel y=-1 when OOB ----
    int2 ev[8];
    {
        const int2* ei2 = (const int2*)ei;
        const int e0 = blockIdx.x * EPB + t;
#pragma unroll
        for (int k2 = 0; k2 < 8; ++k2) {
            int ie = e0 + 256 * k2;
            if (ie < E) ev[k2] = ei2[ie];
            else        { ev[k2].x = 0; ev[k2].y = -1; }
        }
    }

    // ---- stage x (16 nodes x 20 steps, transposed [step][node]) ----
    for (int i = l; i < 16 * TT; i += 64) {
        int nn = i / TT, tt = i - nn * TT;
        int n = n0 + nn; if (n >= N) n = N - 1;
        sx[tt * 16 + nn] = x[(size_t)n * TT + tt];
    }
    // zero h
    {
        uint4 zz = {0, 0, 0, 0};
        uint4* ph = (uint4*)hh;
        uint4* pl = (uint4*)hl;
#pragma unroll
        for (int i = 0; i < 2; ++i) { ph[l + 64 * i] = zz; pl[l + 64 * i] = zz; }
    }

    // ---- W_hh -> hi/lo bf16 B-fragments (in registers, trunc-split) ----
    // frag element: W[16*tt2 + nl][kc*32 + quad*8 + j]
    short8 Bh[4][2], Bl[4][2];
#pragma unroll
    for (int tt2 = 0; tt2 < 4; ++tt2)
#pragma unroll
        for (int kc = 0; kc < 2; ++kc) {
            const float* wr = W_hh + (size_t)(16 * tt2 + nl) * HH + kc * 32 + quad * 8;
            float4 w0 = *(const float4*)(wr);
            float4 w1 = *(const float4*)(wr + 4);
            float wv[8] = {w0.x, w0.y, w0.z, w0.w, w1.x, w1.y, w1.z, w1.w};
            short8 sh, sl;
#pragma unroll
            for (int j = 0; j < 8; ++j) {
                unsigned u  = fbits(wv[j]);
                unsigned hb = u & 0xffff0000u;
                float lo = wv[j] - bcast(hb);
                sh[j] = (short)(hb >> 16);
                sl[j] = (short)(fbits(lo) >> 16);
            }
            Bh[tt2][kc] = sh; Bl[tt2][kc] = sl;
        }

    // ---- v = W_gcn^T w_fc (per-lane column dot; W_fc via scalar loads) ----
    float vl = 0.0f;
#pragma unroll 8
    for (int j = 0; j < HH; ++j) vl = fmaf(W_fc[j], W_gcn[j * HH + l], vl);

    float wih4[4], bs4[4], vv[4];
#pragma unroll
    for (int tt2 = 0; tt2 < 4; ++tt2) {
        int n = nl + 16 * tt2;
        wih4[tt2] = W_ih[n];
        bs4[tt2]  = b_ih[n] + b_hh[n];
        vv[tt2]   = __shfl(vl, n, 64);
    }

    const int ra = (l ^ ((l >> 4) & 1)) * 8;   // A-read offset (shorts)

    f32x4 C[4];

#pragma unroll
    for (int sc = 0; sc < 4; ++sc) {
        // fire 2 deg atomics per chunk (fire-and-forget, drains under MFMA)
        if (ev[2 * sc].y     >= 0) atomicAdd(&degi[ev[2 * sc].y], 1);
        if (ev[2 * sc + 1].y >= 0) atomicAdd(&degi[ev[2 * sc + 1].y], 1);

        for (int s5 = 0; s5 < 5; ++s5) {
            const int step = sc * 5 + s5;
            const float4 xr = *(const float4*)&sx[step * 16 + quad * 4];
#pragma unroll
            for (int tt2 = 0; tt2 < 4; ++tt2) {
                C[tt2][0] = fmaf(xr.x, wih4[tt2], bs4[tt2]);
                C[tt2][1] = fmaf(xr.y, wih4[tt2], bs4[tt2]);
                C[tt2][2] = fmaf(xr.z, wih4[tt2], bs4[tt2]);
                C[tt2][3] = fmaf(xr.w, wih4[tt2], bs4[tt2]);
            }

#pragma unroll
            for (int kc = 0; kc < 2; ++kc) {
                short8 Ah = *(const short8*)&hh[kc * 512 + ra];
                short8 Al = *(const short8*)&hl[kc * 512 + ra];
#pragma unroll
                for (int tt2 = 0; tt2 < 4; ++tt2) {
                    C[tt2] = __builtin_amdgcn_mfma_f32_16x16x32_bf16(Ah, Bh[tt2][kc], C[tt2], 0, 0, 0);
                    C[tt2] = __builtin_amdgcn_mfma_f32_16x16x32_bf16(Ah, Bl[tt2][kc], C[tt2], 0, 0, 0);
                    C[tt2] = __builtin_amdgcn_mfma_f32_16x16x32_bf16(Al, Bh[tt2][kc], C[tt2], 0, 0, 0);
                }
            }

            // tanh + trunc-split + neighbor-pack + swizzled write back
#pragma unroll
            for (int tt2 = 0; tt2 < 4; ++tt2) {
                const int kc_d = tt2 >> 1;
                const int qa   = (nl >> 3) + 2 * (tt2 & 1);
#pragma unroll
                for (int r = 0; r < 4; ++r) {
                    float hv = fast_tanh(C[tt2][r]);
                    C[tt2][r] = hv;
                    unsigned um = fbits(hv);
                    unsigned un = (unsigned)__shfl_xor((int)um, 1, 64);
                    if (!(nl & 1)) {
                        unsigned hiw = (um >> 16) | (un & 0xffff0000u);
                        float lm = hv - bcast(um & 0xffff0000u);
                        float ln = bcast(un) - bcast(un & 0xffff0000u);
                        unsigned low = (fbits(lm) >> 16) | (fbits(ln) & 0xffff0000u);
                        const int m   = quad * 4 + r;
                        const int la  = m + 16 * qa;
                        const int idx = kc_d * 512 + (la ^ ((la >> 4) & 1)) * 8 + (nl & 7);
                        *(unsigned*)&hh[idx] = hiw;
                        *(unsigned*)&hl[idx] = low;
                    }
                }
            }
        }
    }

    // epilogue: z[node] = h . v  (C holds fp32 h: row=quad*4+r, col=nl+16*tt2)
#pragma unroll
    for (int r = 0; r < 4; ++r) {
        float p = 0.0f;
#pragma unroll
        for (int tt2 = 0; tt2 < 4; ++tt2) p = fmaf(C[tt2][r], vv[tt2], p);
        p += __shfl_xor(p, 1, 64);
        p += __shfl_xor(p, 2, 64);
        p += __shfl_xor(p, 4, 64);
        p += __shfl_xor(p, 8, 64);
        if (nl == 0) {
            const int n = n0 + quad * 4 + r;
            if (n < N) z[n] = p;
        }
    }
}

// w[n] = rsqrt(deg[n]+1) * z[n]
__global__ void k_w(const int* __restrict__ degi, const float* __restrict__ z,
                    float* __restrict__ w, int N) {
    int n = blockIdx.x * blockDim.x + threadIdx.x;
    if (n < N) w[n] = __frsqrt_rn((float)degi[n] + 1.0f) * z[n];
}

// S[d] += w[s] — 1 edge/thread, coalesced int2
__global__ void k_edge(const int* __restrict__ ei, const float* __restrict__ w,
                       float* __restrict__ S, int E) {
    int e = blockIdx.x * blockDim.x + threadIdx.x;
    if (e >= E) return;
    int2 p = ((const int2*)ei)[e];
    atomicAdd(&S[p.y], w[p.x]);
}

// out = dinv*(S + dinv*z) + c,  c = w_fc.b_gcn + b_fc
__global__ void k_final(const int* __restrict__ degi, const float* __restrict__ S,
                        const float* __restrict__ z,
                        const float* __restrict__ b_gcn, const float* __restrict__ W_fc,
                        const float* __restrict__ b_fc,
                        float* __restrict__ out, int N)
{
    float c = b_fc[0];
#pragma unroll 8
    for (int j = 0; j < HH; ++j) c = fmaf(W_fc[j], b_gcn[j], c);
    int n = blockIdx.x * blockDim.x + threadIdx.x;
    if (n >= N) return;
    float d = __frsqrt_rn((float)degi[n] + 1.0f);
    out[n] = fmaf(d, S[n] + d * z[n], c);
}

extern "C" void kernel_launch(void* const* d_in, const int* in_sizes, int n_in,
                              void* d_out, int out_size, void* d_ws, size_t ws_size,
                              hipStream_t stream)
{
    const float* x     = (const float*)d_in[0];
    const int*   ei    = (const int*)d_in[1];
    const float* W_ih  = (const float*)d_in[2];
    const float* b_ih  = (const float*)d_in[3];
    const float* W_hh  = (const float*)d_in[4];
    const float* b_hh  = (const float*)d_in[5];
    const float* W_gcn = (const float*)d_in[6];
    const float* b_gcn = (const float*)d_in[7];
    const float* W_fc  = (const float*)d_in[8];
    const float* b_fc  = (const float*)d_in[9];
    float* out = (float*)d_out;

    const int N = in_sizes[0] / TT;
    const int E = in_sizes[1] / 2;

    char* ws = (char*)d_ws;
    size_t off = 0;
    auto alloc = [&](size_t bytes) { void* p = ws + off; off += (bytes + 255) & ~(size_t)255; return p; };
    int*   degi = (int*)  alloc((size_t)N * 4);
    float* S    = (float*)alloc((size_t)N * 4);
    float* z    = (float*)alloc((size_t)N * 4);
    float* w    = (float*)alloc((size_t)N * 4);

    // degi and S adjacent: one memset zeroes both
    size_t span = (size_t)((char*)(S + N) - (char*)degi);
    hipMemsetAsync(degi, 0, span, stream);

    const int rnnBlocks = (N + 63) / 64;   // 1563; EPB*1563 >= E covers all edges
    k_fused<<<rnnBlocks, 256, 0, stream>>>(x, W_ih, b_ih, W_hh, b_hh,
                                           W_gcn, W_fc, ei, degi, z, N, E);
    k_w    <<<(N + 255) / 256, 256, 0, stream>>>(degi, z, w, N);
    k_edge <<<(E + 255) / 256, 256, 0, stream>>>(ei, w, S, E);
    k_final<<<(N + 255) / 256, 256, 0, stream>>>(degi, S, z, b_gcn, W_fc, b_fc, out, N);
}

// Round 11
// 414.427 us; speedup vs baseline: 1.2863x; 1.0375x over previous
//
#include <hip/hip_runtime.h>

#define TT 20
#define HH 64
#define EPB 2048       // edges (deg atomics) per RNN block = 8 per thread
#define NXCD 8

typedef __attribute__((ext_vector_type(8))) short short8;   // 8 bf16 (MFMA A/B frag)
typedef __attribute__((ext_vector_type(4))) float f32x4;    // MFMA C/D frag

__device__ __forceinline__ float fast_tanh(float a) {
    a = fminf(fmaxf(a, -12.0f), 12.0f);
    float e = __builtin_amdgcn_exp2f(a * 2.885390081777927f);
    return (e - 1.0f) * __builtin_amdgcn_rcpf(e + 1.0f);
}

__device__ __forceinline__ unsigned fbits(float f) { union { float f; unsigned u; } v; v.f = f; return v.u; }
__device__ __forceinline__ float bcast(unsigned u) { union { float f; unsigned u; } v; v.u = u; return v.f; }

// hardware XCD id (0..7) — wave-uniform [learn_hip m09]
__device__ __forceinline__ unsigned get_xcd() {
    unsigned x;
    asm volatile("s_getreg_b32 %0, hwreg(HW_REG_XCC_ID)" : "=s"(x));
    return x & (NXCD - 1);
}

// Fused: every block = 4 independent RNN waves (16 nodes each, wave-private LDS,
// no barriers) + a 2048-edge deg-histogram slice via XCD-local L2 atomics.
__global__ __launch_bounds__(256, 3) void k_fused(
    const float* __restrict__ x,
    const float* __restrict__ W_ih, const float* __restrict__ b_ih,
    const float* __restrict__ W_hh, const float* __restrict__ b_hh,
    const float* __restrict__ W_gcn, const float* __restrict__ W_fc,
    const int* __restrict__ ei,
    int* __restrict__ degr, float* __restrict__ z,
    int N, int E)
{
    __shared__ __align__(16) unsigned short sHh[4][1024];
    __shared__ __align__(16) unsigned short sHl[4][1024];
    __shared__ __align__(16) float sX[4][16 * TT];

    const int t    = threadIdx.x;
    const int w    = t >> 6;
    const int l    = t & 63;
    const int nl   = l & 15;
    const int quad = l >> 4;
    const int n0   = blockIdx.x * 64 + w * 16;

    int* degx = degr + (size_t)get_xcd() * N;   // this XCD's private replica

    unsigned short* hh = sHh[w];
    unsigned short* hl = sHl[w];
    float*          sx = sX[w];

    // ---- edge slice loads (coalesced int2), sentinel y=-1 when OOB ----
    int2 ev[8];
    {
        const int2* ei2 = (const int2*)ei;
        const int e0 = blockIdx.x * EPB + t;
#pragma unroll
        for (int k2 = 0; k2 < 8; ++k2) {
            int ie = e0 + 256 * k2;
            if (ie < E) ev[k2] = ei2[ie];
            else        { ev[k2].x = 0; ev[k2].y = -1; }
        }
    }

    // ---- stage x (16 nodes x 20 steps, transposed [step][node]) ----
    for (int i = l; i < 16 * TT; i += 64) {
        int nn = i / TT, tt = i - nn * TT;
        int n = n0 + nn; if (n >= N) n = N - 1;
        sx[tt * 16 + nn] = x[(size_t)n * TT + tt];
    }
    // zero h
    {
        uint4 zz = {0, 0, 0, 0};
        uint4* ph = (uint4*)hh;
        uint4* pl = (uint4*)hl;
#pragma unroll
        for (int i = 0; i < 2; ++i) { ph[l + 64 * i] = zz; pl[l + 64 * i] = zz; }
    }

    // ---- W_hh -> hi/lo bf16 B-fragments (registers, trunc-split) ----
    short8 Bh[4][2], Bl[4][2];
#pragma unroll
    for (int tt2 = 0; tt2 < 4; ++tt2)
#pragma unroll
        for (int kc = 0; kc < 2; ++kc) {
            const float* wr = W_hh + (size_t)(16 * tt2 + nl) * HH + kc * 32 + quad * 8;
            float4 w0 = *(const float4*)(wr);
            float4 w1 = *(const float4*)(wr + 4);
            float wv[8] = {w0.x, w0.y, w0.z, w0.w, w1.x, w1.y, w1.z, w1.w};
            short8 sh, sl;
#pragma unroll
            for (int j = 0; j < 8; ++j) {
                unsigned u  = fbits(wv[j]);
                unsigned hb = u & 0xffff0000u;
                float lo = wv[j] - bcast(hb);
                sh[j] = (short)(hb >> 16);
                sl[j] = (short)(fbits(lo) >> 16);
            }
            Bh[tt2][kc] = sh; Bl[tt2][kc] = sl;
        }

    // ---- v = W_gcn^T w_fc ----
    float vl = 0.0f;
#pragma unroll 8
    for (int j = 0; j < HH; ++j) vl = fmaf(W_fc[j], W_gcn[j * HH + l], vl);

    float wih4[4], bs4[4], vv[4];
#pragma unroll
    for (int tt2 = 0; tt2 < 4; ++tt2) {
        int n = nl + 16 * tt2;
        wih4[tt2] = W_ih[n];
        bs4[tt2]  = b_ih[n] + b_hh[n];
        vv[tt2]   = __shfl(vl, n, 64);
    }

    const int ra = (l ^ ((l >> 4) & 1)) * 8;   // A-read offset (shorts)

    f32x4 C[4];

#pragma unroll
    for (int sc = 0; sc < 4; ++sc) {
        // 2 deg atomics per chunk — XCD-local L2, drains under MFMA
        if (ev[2 * sc].y >= 0)
            __hip_atomic_fetch_add(&degx[ev[2 * sc].y], 1, __ATOMIC_RELAXED, __HIP_MEMORY_SCOPE_WORKGROUP);
        if (ev[2 * sc + 1].y >= 0)
            __hip_atomic_fetch_add(&degx[ev[2 * sc + 1].y], 1, __ATOMIC_RELAXED, __HIP_MEMORY_SCOPE_WORKGROUP);

        for (int s5 = 0; s5 < 5; ++s5) {
            const int step = sc * 5 + s5;
            const float4 xr = *(const float4*)&sx[step * 16 + quad * 4];
#pragma unroll
            for (int tt2 = 0; tt2 < 4; ++tt2) {
                C[tt2][0] = fmaf(xr.x, wih4[tt2], bs4[tt2]);
                C[tt2][1] = fmaf(xr.y, wih4[tt2], bs4[tt2]);
                C[tt2][2] = fmaf(xr.z, wih4[tt2], bs4[tt2]);
                C[tt2][3] = fmaf(xr.w, wih4[tt2], bs4[tt2]);
            }

#pragma unroll
            for (int kc = 0; kc < 2; ++kc) {
                short8 Ah = *(const short8*)&hh[kc * 512 + ra];
                short8 Al = *(const short8*)&hl[kc * 512 + ra];
#pragma unroll
                for (int tt2 = 0; tt2 < 4; ++tt2) {
                    C[tt2] = __builtin_amdgcn_mfma_f32_16x16x32_bf16(Ah, Bh[tt2][kc], C[tt2], 0, 0, 0);
                    C[tt2] = __builtin_amdgcn_mfma_f32_16x16x32_bf16(Ah, Bl[tt2][kc], C[tt2], 0, 0, 0);
                    C[tt2] = __builtin_amdgcn_mfma_f32_16x16x32_bf16(Al, Bh[tt2][kc], C[tt2], 0, 0, 0);
                }
            }

            // tanh + trunc-split + neighbor-pack + swizzled write back
#pragma unroll
            for (int tt2 = 0; tt2 < 4; ++tt2) {
                const int kc_d = tt2 >> 1;
                const int qa   = (nl >> 3) + 2 * (tt2 & 1);
#pragma unroll
                for (int r = 0; r < 4; ++r) {
                    float hv = fast_tanh(C[tt2][r]);
                    C[tt2][r] = hv;
                    unsigned um = fbits(hv);
                    unsigned un = (unsigned)__shfl_xor((int)um, 1, 64);
                    if (!(nl & 1)) {
                        unsigned hiw = (um >> 16) | (un & 0xffff0000u);
                        float lm = hv - bcast(um & 0xffff0000u);
                        float ln = bcast(un) - bcast(un & 0xffff0000u);
                        unsigned low = (fbits(lm) >> 16) | (fbits(ln) & 0xffff0000u);
                        const int m   = quad * 4 + r;
                        const int la  = m + 16 * qa;
                        const int idx = kc_d * 512 + (la ^ ((la >> 4) & 1)) * 8 + (nl & 7);
                        *(unsigned*)&hh[idx] = hiw;
                        *(unsigned*)&hl[idx] = low;
                    }
                }
            }
        }
    }

    // epilogue: z[node] = h . v
#pragma unroll
    for (int r = 0; r < 4; ++r) {
        float p = 0.0f;
#pragma unroll
        for (int tt2 = 0; tt2 < 4; ++tt2) p = fmaf(C[tt2][r], vv[tt2], p);
        p += __shfl_xor(p, 1, 64);
        p += __shfl_xor(p, 2, 64);
        p += __shfl_xor(p, 4, 64);
        p += __shfl_xor(p, 8, 64);
        if (nl == 0) {
            const int n = n0 + quad * 4 + r;
            if (n < N) z[n] = p;
        }
    }
}

// reduce deg replicas; dinv = rsqrt(deg+1); w = dinv*z
__global__ void k_w(const int* __restrict__ degr, const float* __restrict__ z,
                    float* __restrict__ dinv, float* __restrict__ w, int N) {
    int n = blockIdx.x * blockDim.x + threadIdx.x;
    if (n >= N) return;
    int d = 0;
#pragma unroll
    for (int k = 0; k < NXCD; ++k) d += degr[(size_t)k * N + n];
    float di = __frsqrt_rn((float)d + 1.0f);
    dinv[n] = di;
    w[n] = di * z[n];
}

// S_rep[xcd][d] += w[s] — XCD-local L2 atomics
__global__ void k_edge(const int* __restrict__ ei, const float* __restrict__ w,
                       float* __restrict__ Srep, int E, int N) {
    float* Sx = Srep + (size_t)get_xcd() * N;
    int e = blockIdx.x * blockDim.x + threadIdx.x;
    if (e >= E) return;
    int2 p = ((const int2*)ei)[e];
    __hip_atomic_fetch_add(&Sx[p.y], w[p.x], __ATOMIC_RELAXED, __HIP_MEMORY_SCOPE_WORKGROUP);
}

// out = dinv*(sum S_rep + dinv*z) + c,  c = w_fc.b_gcn + b_fc
__global__ void k_final(const float* __restrict__ dinv, const float* __restrict__ Srep,
                        const float* __restrict__ z,
                        const float* __restrict__ b_gcn, const float* __restrict__ W_fc,
                        const float* __restrict__ b_fc,
                        float* __restrict__ out, int N)
{
    float c = b_fc[0];
#pragma unroll 8
    for (int j = 0; j < HH; ++j) c = fmaf(W_fc[j], b_gcn[j], c);
    int n = blockIdx.x * blockDim.x + threadIdx.x;
    if (n >= N) return;
    float S = 0.0f;
#pragma unroll
    for (int k = 0; k < NXCD; ++k) S += Srep[(size_t)k * N + n];
    float d = dinv[n];
    out[n] = fmaf(d, S + d * z[n], c);
}

extern "C" void kernel_launch(void* const* d_in, const int* in_sizes, int n_in,
                              void* d_out, int out_size, void* d_ws, size_t ws_size,
                              hipStream_t stream)
{
    const float* x     = (const float*)d_in[0];
    const int*   ei    = (const int*)d_in[1];
    const float* W_ih  = (const float*)d_in[2];
    const float* b_ih  = (const float*)d_in[3];
    const float* W_hh  = (const float*)d_in[4];
    const float* b_hh  = (const float*)d_in[5];
    const float* W_gcn = (const float*)d_in[6];
    const float* b_gcn = (const float*)d_in[7];
    const float* W_fc  = (const float*)d_in[8];
    const float* b_fc  = (const float*)d_in[9];
    float* out = (float*)d_out;

    const int N = in_sizes[0] / TT;
    const int E = in_sizes[1] / 2;

    char* ws = (char*)d_ws;
    size_t off = 0;
    auto alloc = [&](size_t bytes) { void* p = ws + off; off += (bytes + 255) & ~(size_t)255; return p; };
    int*   degr = (int*)  alloc((size_t)NXCD * N * 4);
    float* Srep = (float*)alloc((size_t)NXCD * N * 4);
    float* z    = (float*)alloc((size_t)N * 4);
    float* dinv = (float*)alloc((size_t)N * 4);
    float* w    = (float*)alloc((size_t)N * 4);

    // degr and Srep adjacent: one memset zeroes both replica sets
    size_t span = (size_t)((char*)(Srep + (size_t)NXCD * N) - (char*)degr);
    hipMemsetAsync(degr, 0, span, stream);

    const int rnnBlocks = (N + 63) / 64;   // 1563; EPB*1563 >= E covers all edges
    k_fused<<<rnnBlocks, 256, 0, stream>>>(x, W_ih, b_ih, W_hh, b_hh,
                                           W_gcn, W_fc, ei, degr, z, N, E);
    k_w    <<<(N + 255) / 256, 256, 0, stream>>>(degr, z, dinv, w, N);
    k_edge <<<(E + 255) / 256, 256, 0, stream>>>(ei, w, Srep, E, N);
    k_final<<<(N + 255) / 256, 256, 0, stream>>>(dinv, Srep, z, b_gcn, W_fc, b_fc, out, N);
}